// Round 3
// baseline (79.302 us; speedup 1.0000x reference)
//
#include <hip/hip_runtime.h>
#include <math.h>

#define Bn 4
#define Pn 24
#define Gn 24
#define Hd 512
#define Wd 512
#define NOBJ (Bn * Pn)
#define SPLIT 16
#define TOTAL_BLOCKS (NOBJ * SPLIT)
#define IOU_THRESH 0.5f
#define LOG_CLAMP -100.0f

// ws layout:
//   offset 0:  unsigned int ticket counter (memset to 0 each launch)
//   offset 64: float slots[NOBJ][SPLIT][4]  (bce_sum, inter, sum_p, sum_t)
// Slots are written ONLY for kept objects and read ONLY for kept objects,
// so they need no zero-init. All cross-block traffic is agent-scope atomic
// (per-XCD L2s are not coherent -- G16).

__device__ __forceinline__ void match_obj(const float* __restrict__ pred_boxes,
                                          const float* __restrict__ gt_boxes,
                                          const int* __restrict__ pred_valid,
                                          const int* __restrict__ gt_valid,
                                          int obj, int& keep, int& gidx,
                                          int& y1, int& x1, int& y2, int& x2) {
    int b = obj / Pn;
    const float* pb = pred_boxes + (size_t)obj * 4;
    float a0 = pb[0], a1 = pb[1], a2 = pb[2], a3 = pb[3];
    float area_a = (a2 - a0) * (a3 - a1);
    float best = -1.0f;
    gidx = 0;
    for (int g = 0; g < Gn; ++g) {
        const float* gb = gt_boxes + ((size_t)b * Gn + g) * 4;
        float b0 = gb[0], b1 = gb[1], b2 = gb[2], b3 = gb[3];
        float area_b = (b2 - b0) * (b3 - b1);
        float ih = fmaxf(fminf(a2, b2) - fmaxf(a0, b0), 0.0f);
        float iw = fmaxf(fminf(a3, b3) - fmaxf(a1, b1), 0.0f);
        float inter = ih * iw;
        float uni = area_a + area_b - inter;
        float iou = (uni == 0.0f) ? 0.0f : inter / uni;
        if (gt_valid[b * Gn + g] == 0) iou = -1.0f;
        if (iou > best) { best = iou; gidx = g; }  // first-max == jnp.argmax
    }
    keep = (best >= IOU_THRESH) && (pred_valid[obj] != 0);
    // jnp.round is round-half-to-even -> rintf (default FE_TONEAREST)
    y1 = max(0, (int)rintf(a0 * (float)Hd));
    x1 = max(0, (int)rintf(a1 * (float)Wd));
    y2 = min((int)rintf(a2 * (float)Hd), Hd - 1);
    x2 = min((int)rintf(a3 * (float)Wd), Wd - 1);
}

__global__ __launch_bounds__(256) void fused_kernel(
    const float* __restrict__ pred_masks, const float* __restrict__ gt_masks,
    const float* __restrict__ pred_boxes, const float* __restrict__ gt_boxes,
    const int* __restrict__ pred_valid, const int* __restrict__ gt_valid,
    float* __restrict__ slots, unsigned int* __restrict__ counter,
    float* __restrict__ out) {
    int bid = (int)blockIdx.x;
    int obj = bid >> 4;            // SPLIT = 16
    int part = bid & (SPLIT - 1);

    int keep, gidx, y1, x1, y2, x2;
    match_obj(pred_boxes, gt_boxes, pred_valid, gt_valid, obj, keep, gidx, y1, x1, y2, x2);

    float v0 = 0.0f, v1 = 0.0f, v2 = 0.0f, v3 = 0.0f;
    if (keep) {
        int Hr = y2 - y1 + 1, Wr = x2 - x1 + 1;
        if (Hr > 0 && Wr > 0) {
            int N = Hr * Wr;
            const float* pm = pred_masks + (size_t)obj * Hd * Wd;
            const float* gm = gt_masks + ((size_t)(obj / Pn) * Gn + gidx) * Hd * Wd;
            for (int idx = part * 256 + (int)threadIdx.x; idx < N; idx += SPLIT * 256) {
                int r = y1 + idx / Wr;
                int c = x1 + idx % Wr;
                float pv = pm[r * Wd + c];
                float tv = gm[r * Wd + c];
                // t is exactly 0/1: pick the needed log argument
                float xarg = (tv > 0.5f) ? pv : (1.0f - pv);
                v0 -= fmaxf(__logf(xarg), LOG_CLAMP);
                v1 = fmaf(pv, tv, v1);
                v2 += pv;
                v3 += tv;
            }
        }
    }

    // block reduce 256 -> 4 sums
    for (int o = 32; o > 0; o >>= 1) {
        v0 += __shfl_down(v0, o, 64);
        v1 += __shfl_down(v1, o, 64);
        v2 += __shfl_down(v2, o, 64);
        v3 += __shfl_down(v3, o, 64);
    }
    __shared__ float red[4][4];
    int lane = threadIdx.x & 63, w = threadIdx.x >> 6;
    if (lane == 0) { red[w][0] = v0; red[w][1] = v1; red[w][2] = v2; red[w][3] = v3; }
    __syncthreads();
    if (keep && threadIdx.x < 4) {
        float s = red[0][threadIdx.x] + red[1][threadIdx.x] +
                  red[2][threadIdx.x] + red[3][threadIdx.x];
        __hip_atomic_store(&slots[(size_t)bid * 4 + threadIdx.x], s,
                           __ATOMIC_RELEASE, __HIP_MEMORY_SCOPE_AGENT);
    }
    __syncthreads();  // all slot stores drained before ticket

    __shared__ unsigned int tkt;
    if (threadIdx.x == 0) {
        __threadfence();
        tkt = __hip_atomic_fetch_add(counter, 1u, __ATOMIC_ACQ_REL,
                                     __HIP_MEMORY_SCOPE_AGENT);
    }
    __syncthreads();

    if (tkt == TOTAL_BLOCKS - 1) {
        // last block: finalize in-place
        int i = (int)threadIdx.x;
        float loss = 0.0f, nk = 0.0f;
        if (i < NOBJ) {
            int k2, g2, yy1, xx1, yy2, xx2;
            match_obj(pred_boxes, gt_boxes, pred_valid, gt_valid, i, k2, g2, yy1, xx1, yy2, xx2);
            if (k2) {
                nk = 1.0f;
                float s0 = 0.0f, s1 = 0.0f, s2 = 0.0f, s3 = 0.0f;
                const float* sl = slots + (size_t)i * SPLIT * 4;
                #pragma unroll
                for (int p = 0; p < SPLIT; ++p) {
                    s0 += __hip_atomic_load(&sl[p * 4 + 0], __ATOMIC_RELAXED, __HIP_MEMORY_SCOPE_AGENT);
                    s1 += __hip_atomic_load(&sl[p * 4 + 1], __ATOMIC_RELAXED, __HIP_MEMORY_SCOPE_AGENT);
                    s2 += __hip_atomic_load(&sl[p * 4 + 2], __ATOMIC_RELAXED, __HIP_MEMORY_SCOPE_AGENT);
                    s3 += __hip_atomic_load(&sl[p * 4 + 3], __ATOMIC_RELAXED, __HIP_MEMORY_SCOPE_AGENT);
                }
                float cnt = (yy2 >= yy1 && xx2 >= xx1)
                              ? (float)((yy2 - yy1 + 1) * (xx2 - xx1 + 1)) : 0.0f;
                float bce = s0 / fmaxf(cnt, 1.0f);
                float dice = 1.0f - (2.0f * s1 + 1.0f) / (s2 + s3 + 1.0f);
                loss = bce + dice;
            }
        }
        for (int o = 32; o > 0; o >>= 1) {
            loss += __shfl_down(loss, o, 64);
            nk += __shfl_down(nk, o, 64);
        }
        __shared__ float red2[2][4];
        if ((threadIdx.x & 63) == 0) {
            red2[0][threadIdx.x >> 6] = loss;
            red2[1][threadIdx.x >> 6] = nk;
        }
        __syncthreads();
        if (threadIdx.x == 0) {
            float total = red2[0][0] + red2[0][1] + red2[0][2] + red2[0][3];
            float n = red2[1][0] + red2[1][1] + red2[1][2] + red2[1][3];
            out[0] = total / fmaxf(n, 1.0f);
        }
    }
}

extern "C" void kernel_launch(void* const* d_in, const int* in_sizes, int n_in,
                              void* d_out, int out_size, void* d_ws, size_t ws_size,
                              hipStream_t stream) {
    const float* pred_masks = (const float*)d_in[0];
    const float* pred_boxes = (const float*)d_in[1];
    const float* gt_boxes   = (const float*)d_in[2];
    const float* gt_masks   = (const float*)d_in[3];
    const int*   pred_valid = (const int*)d_in[4];
    const int*   gt_valid   = (const int*)d_in[5];
    float* out = (float*)d_out;

    unsigned int* counter = (unsigned int*)d_ws;
    float* slots = (float*)((char*)d_ws + 64);

    hipMemsetAsync(counter, 0, sizeof(unsigned int), stream);
    fused_kernel<<<TOTAL_BLOCKS, 256, 0, stream>>>(
        pred_masks, gt_masks, pred_boxes, gt_boxes, pred_valid, gt_valid,
        slots, counter, out);
}

// Round 4
// 21.847 us; speedup vs baseline: 3.6298x; 3.6298x over previous
//
#include <hip/hip_runtime.h>
#include <math.h>

#define Bn 4
#define Pn 24
#define Gn 24
#define Hd 512
#define Wd 512
#define NOBJ (Bn * Pn)
#define SPLIT 8
#define IOU_THRESH 0.5f
#define LOG_CLAMP -100.0f

// ws layout: acc float[NOBJ][SPLIT][4]  (bce_sum, inter, sum_p, sum_t)
// Every block writes its slot unconditionally -> no zero-init, no atomics.

__device__ __forceinline__ void match_obj(const float* __restrict__ pred_boxes,
                                          const float* __restrict__ gt_boxes,
                                          const int* __restrict__ pred_valid,
                                          const int* __restrict__ gt_valid,
                                          int obj, int& keep, int& gidx,
                                          int& y1, int& x1, int& y2, int& x2) {
    int b = obj / Pn;
    const float* pb = pred_boxes + (size_t)obj * 4;
    float a0 = pb[0], a1 = pb[1], a2 = pb[2], a3 = pb[3];
    float area_a = (a2 - a0) * (a3 - a1);
    float best = -1.0f;
    gidx = 0;
    #pragma unroll
    for (int g = 0; g < Gn; ++g) {
        const float* gb = gt_boxes + ((size_t)b * Gn + g) * 4;
        float b0 = gb[0], b1 = gb[1], b2 = gb[2], b3 = gb[3];
        float area_b = (b2 - b0) * (b3 - b1);
        float ih = fmaxf(fminf(a2, b2) - fmaxf(a0, b0), 0.0f);
        float iw = fmaxf(fminf(a3, b3) - fmaxf(a1, b1), 0.0f);
        float inter = ih * iw;
        float uni = area_a + area_b - inter;
        float iou = (uni == 0.0f) ? 0.0f : inter / uni;
        if (gt_valid[b * Gn + g] == 0) iou = -1.0f;
        if (iou > best) { best = iou; gidx = g; }  // first-max == jnp.argmax
    }
    keep = (best >= IOU_THRESH) && (pred_valid[obj] != 0);
    // jnp.round is round-half-to-even -> rintf (default FE_TONEAREST)
    y1 = max(0, (int)rintf(a0 * (float)Hd));
    x1 = max(0, (int)rintf(a1 * (float)Wd));
    y2 = min((int)rintf(a2 * (float)Hd), Hd - 1);
    x2 = min((int)rintf(a3 * (float)Wd), Wd - 1);
}

__global__ __launch_bounds__(256) void region_kernel(
    const float* __restrict__ pred_masks, const float* __restrict__ gt_masks,
    const float* __restrict__ pred_boxes, const float* __restrict__ gt_boxes,
    const int* __restrict__ pred_valid, const int* __restrict__ gt_valid,
    float* __restrict__ acc) {
    int obj = blockIdx.x;   // b*Pn + p
    int part = blockIdx.y;  // 0..SPLIT-1

    int keep, gidx, y1, x1, y2, x2;
    match_obj(pred_boxes, gt_boxes, pred_valid, gt_valid, obj, keep, gidx, y1, x1, y2, x2);

    float v0 = 0.0f, v1 = 0.0f, v2 = 0.0f, v3 = 0.0f;
    if (keep) {
        int Hr = y2 - y1 + 1, Wr = x2 - x1 + 1;
        if (Hr > 0 && Wr > 0) {
            int N = Hr * Wr;
            int s = (part * 256 + (int)threadIdx.x) * 4;  // 4 px per group
            if (s < N) {
                const float* pm = pred_masks + (size_t)obj * Hd * Wd;
                const float* gm = gt_masks + ((size_t)(obj / Pn) * Gn + gidx) * Hd * Wd;
                const int step = SPLIT * 256 * 4;          // px advanced per sweep
                int r = s / Wr;                            // the ONLY runtime div
                int c = s - r * Wr;
                int dr = step / Wr, dc = step - (step / Wr) * Wr;  // const per object
                while (true) {
                    const float* prow = pm + (y1 + r) * Wd + x1;
                    const float* trow = gm + (y1 + r) * Wd + x1;
                    if (c + 4 <= Wr && s + 4 <= N) {
                        // fast path: 8 independent loads -> MLP
                        float p0 = prow[c], p1 = prow[c + 1], p2 = prow[c + 2], p3 = prow[c + 3];
                        float q0 = trow[c], q1 = trow[c + 1], q2 = trow[c + 2], q3 = trow[c + 3];
                        float a0 = (q0 > 0.5f) ? p0 : 1.0f - p0;
                        float a1 = (q1 > 0.5f) ? p1 : 1.0f - p1;
                        float a2 = (q2 > 0.5f) ? p2 : 1.0f - p2;
                        float a3 = (q3 > 0.5f) ? p3 : 1.0f - p3;
                        v0 -= (fmaxf(__logf(a0), LOG_CLAMP) + fmaxf(__logf(a1), LOG_CLAMP)) +
                              (fmaxf(__logf(a2), LOG_CLAMP) + fmaxf(__logf(a3), LOG_CLAMP));
                        v1 += ((q0 > 0.5f ? p0 : 0.0f) + (q1 > 0.5f ? p1 : 0.0f)) +
                              ((q2 > 0.5f ? p2 : 0.0f) + (q3 > 0.5f ? p3 : 0.0f));
                        v2 += (p0 + p1) + (p2 + p3);
                        v3 += (q0 + q1) + (q2 + q3);
                    } else {
                        // row-wrap or tail: per-pixel walk
                        int lim = min(4, N - s);
                        int rr = r, cc = c;
                        for (int k = 0; k < lim; ++k) {
                            float pv = pm[(y1 + rr) * Wd + x1 + cc];
                            float tv = gm[(y1 + rr) * Wd + x1 + cc];
                            float xa = (tv > 0.5f) ? pv : 1.0f - pv;
                            v0 -= fmaxf(__logf(xa), LOG_CLAMP);
                            v1 += (tv > 0.5f) ? pv : 0.0f;
                            v2 += pv;
                            v3 += tv;
                            if (++cc == Wr) { cc = 0; ++rr; }
                        }
                    }
                    s += step;
                    if (s >= N) break;
                    c += dc; r += dr;
                    if (c >= Wr) { c -= Wr; ++r; }
                }
            }
        }
    }

    // block reduce 256 -> 4 sums
    for (int o = 32; o > 0; o >>= 1) {
        v0 += __shfl_down(v0, o, 64);
        v1 += __shfl_down(v1, o, 64);
        v2 += __shfl_down(v2, o, 64);
        v3 += __shfl_down(v3, o, 64);
    }
    __shared__ float red[4][4];
    int lane = threadIdx.x & 63, w = threadIdx.x >> 6;
    if (lane == 0) { red[w][0] = v0; red[w][1] = v1; red[w][2] = v2; red[w][3] = v3; }
    __syncthreads();
    if (threadIdx.x < 4) {
        float sfin = red[0][threadIdx.x] + red[1][threadIdx.x] +
                     red[2][threadIdx.x] + red[3][threadIdx.x];
        acc[((size_t)obj * SPLIT + part) * 4 + threadIdx.x] = sfin;  // unconditional slot write
    }
}

__global__ __launch_bounds__(128) void finalize_kernel(
    const float* __restrict__ acc,
    const float* __restrict__ pred_boxes, const float* __restrict__ gt_boxes,
    const int* __restrict__ pred_valid, const int* __restrict__ gt_valid,
    float* __restrict__ out) {
    int i = threadIdx.x;  // 128 threads, 2 waves
    float loss = 0.0f, nk = 0.0f;
    if (i < NOBJ) {
        int keep, gidx, y1, x1, y2, x2;
        match_obj(pred_boxes, gt_boxes, pred_valid, gt_valid, i, keep, gidx, y1, x1, y2, x2);
        if (keep) {
            nk = 1.0f;
            float s0 = 0.0f, s1 = 0.0f, s2 = 0.0f, s3 = 0.0f;
            const float* a = acc + (size_t)i * SPLIT * 4;
            #pragma unroll
            for (int p = 0; p < SPLIT; ++p) {
                s0 += a[p * 4 + 0];
                s1 += a[p * 4 + 1];
                s2 += a[p * 4 + 2];
                s3 += a[p * 4 + 3];
            }
            float cnt = (y2 >= y1 && x2 >= x1) ? (float)((y2 - y1 + 1) * (x2 - x1 + 1)) : 0.0f;
            float bce = s0 / fmaxf(cnt, 1.0f);
            float dice = 1.0f - (2.0f * s1 + 1.0f) / (s2 + s3 + 1.0f);
            loss = bce + dice;
        }
    }
    float v0 = loss, v1 = nk;
    for (int o = 32; o > 0; o >>= 1) {
        v0 += __shfl_down(v0, o, 64);
        v1 += __shfl_down(v1, o, 64);
    }
    __shared__ float red[2][2];
    if ((threadIdx.x & 63) == 0) { red[threadIdx.x >> 6][0] = v0; red[threadIdx.x >> 6][1] = v1; }
    __syncthreads();
    if (threadIdx.x == 0) {
        float total = red[0][0] + red[1][0];
        float nobj = red[0][1] + red[1][1];
        out[0] = total / fmaxf(nobj, 1.0f);
    }
}

extern "C" void kernel_launch(void* const* d_in, const int* in_sizes, int n_in,
                              void* d_out, int out_size, void* d_ws, size_t ws_size,
                              hipStream_t stream) {
    const float* pred_masks = (const float*)d_in[0];
    const float* pred_boxes = (const float*)d_in[1];
    const float* gt_boxes   = (const float*)d_in[2];
    const float* gt_masks   = (const float*)d_in[3];
    const int*   pred_valid = (const int*)d_in[4];
    const int*   gt_valid   = (const int*)d_in[5];
    float* out = (float*)d_out;
    float* acc = (float*)d_ws;  // [NOBJ][SPLIT][4]

    region_kernel<<<dim3(NOBJ, SPLIT), 256, 0, stream>>>(
        pred_masks, gt_masks, pred_boxes, gt_boxes, pred_valid, gt_valid, acc);
    finalize_kernel<<<1, 128, 0, stream>>>(
        acc, pred_boxes, gt_boxes, pred_valid, gt_valid, out);
}

// Round 5
// 18.410 us; speedup vs baseline: 4.3076x; 1.1867x over previous
//
#include <hip/hip_runtime.h>
#include <math.h>

#define Bn 4
#define Pn 24
#define Gn 24
#define Hd 512
#define Wd 512
#define NOBJ (Bn * Pn)
#define SPLIT 8
#define IOU_THRESH 0.5f
#define LOG_CLAMP -100.0f

// ws layout: acc float[NOBJ][SPLIT][4]  (bce_sum, inter, sum_p, sum_t)
// Every block writes its slot unconditionally -> no zero-init, no atomics.

__device__ __forceinline__ void match_obj(const float* __restrict__ pred_boxes,
                                          const float* __restrict__ gt_boxes,
                                          const int* __restrict__ pred_valid,
                                          const int* __restrict__ gt_valid,
                                          int obj, int& keep, int& gidx,
                                          int& y1, int& x1, int& y2, int& x2) {
    int b = obj / Pn;
    const float* pb = pred_boxes + (size_t)obj * 4;
    float a0 = pb[0], a1 = pb[1], a2 = pb[2], a3 = pb[3];
    float area_a = (a2 - a0) * (a3 - a1);
    float best = -1.0f;
    gidx = 0;
    #pragma unroll
    for (int g = 0; g < Gn; ++g) {
        const float* gb = gt_boxes + ((size_t)b * Gn + g) * 4;
        float b0 = gb[0], b1 = gb[1], b2 = gb[2], b3 = gb[3];
        float area_b = (b2 - b0) * (b3 - b1);
        float ih = fmaxf(fminf(a2, b2) - fmaxf(a0, b0), 0.0f);
        float iw = fmaxf(fminf(a3, b3) - fmaxf(a1, b1), 0.0f);
        float inter = ih * iw;
        float uni = area_a + area_b - inter;
        float iou = (uni == 0.0f) ? 0.0f : inter / uni;
        if (gt_valid[b * Gn + g] == 0) iou = -1.0f;
        if (iou > best) { best = iou; gidx = g; }  // first-max == jnp.argmax
    }
    keep = (best >= IOU_THRESH) && (pred_valid[obj] != 0);
    // jnp.round is round-half-to-even -> rintf (default FE_TONEAREST)
    y1 = max(0, (int)rintf(a0 * (float)Hd));
    x1 = max(0, (int)rintf(a1 * (float)Wd));
    y2 = min((int)rintf(a2 * (float)Hd), Hd - 1);
    x2 = min((int)rintf(a3 * (float)Wd), Wd - 1);
}

__global__ __launch_bounds__(256) void region_kernel(
    const float* __restrict__ pred_masks, const float* __restrict__ gt_masks,
    const float* __restrict__ pred_boxes, const float* __restrict__ gt_boxes,
    const int* __restrict__ pred_valid, const int* __restrict__ gt_valid,
    float* __restrict__ acc) {
    int obj = blockIdx.x;   // b*Pn + p
    int part = blockIdx.y;  // 0..SPLIT-1

    int keep, gidx, y1, x1, y2, x2;
    match_obj(pred_boxes, gt_boxes, pred_valid, gt_valid, obj, keep, gidx, y1, x1, y2, x2);

    float v0 = 0.0f, v1 = 0.0f, v2 = 0.0f, v3 = 0.0f;
    if (keep && y2 >= y1 && x2 >= x1) {
        int Hr = y2 - y1 + 1;
        int Wr = x2 - x1 + 1;
        int x1a = x1 & ~3;                    // 16B-aligned start column
        int W4 = (x2 >> 2) - (x1 >> 2) + 1;   // aligned 4-px groups covering [x1,x2]
        int N4 = Hr * W4;
        int idx = part * 256 + (int)threadIdx.x;
        if (idx < N4) {
            const float* pm = pred_masks + (size_t)obj * Hd * Wd + x1a;
            const float* gm = gt_masks + ((size_t)(obj / Pn) * Gn + gidx) * Hd * Wd + x1a;
            const int step = SPLIT * 256;     // groups advanced per sweep
            int r = idx / W4;                 // one div per thread
            int c = idx - r * W4;
            int dr = step / W4;               // one more div per thread
            int dc = step - dr * W4;
            int rel0 = x1a - x1;              // -3..0
            while (true) {
                int off = (y1 + r) * Wd + (c << 2);     // 16B-aligned offset
                float4 p4 = *reinterpret_cast<const float4*>(pm + off);
                float4 q4 = *reinterpret_cast<const float4*>(gm + off);
                int rel = rel0 + (c << 2);              // col - x1 of pixel 0
                // per-pixel in-range mask: 0 <= rel+k < Wr  (single unsigned cmp)
                bool m0 = (unsigned)(rel + 0) < (unsigned)Wr;
                bool m1 = (unsigned)(rel + 1) < (unsigned)Wr;
                bool m2 = (unsigned)(rel + 2) < (unsigned)Wr;
                bool m3 = (unsigned)(rel + 3) < (unsigned)Wr;
                float p0 = m0 ? p4.x : 0.0f, q0 = m0 ? q4.x : 0.0f;
                float p1 = m1 ? p4.y : 0.0f, q1 = m1 ? q4.y : 0.0f;
                float p2 = m2 ? p4.z : 0.0f, q2 = m2 ? q4.z : 0.0f;
                float p3 = m3 ? p4.w : 0.0f, q3 = m3 ? q4.w : 0.0f;
                // t is exactly 0/1: pick needed log arg; masked-out -> 1.0 (log = 0)
                float a0 = m0 ? ((q4.x > 0.5f) ? p4.x : 1.0f - p4.x) : 1.0f;
                float a1 = m1 ? ((q4.y > 0.5f) ? p4.y : 1.0f - p4.y) : 1.0f;
                float a2 = m2 ? ((q4.z > 0.5f) ? p4.z : 1.0f - p4.z) : 1.0f;
                float a3 = m3 ? ((q4.w > 0.5f) ? p4.w : 1.0f - p4.w) : 1.0f;
                v0 -= (fmaxf(__logf(a0), LOG_CLAMP) + fmaxf(__logf(a1), LOG_CLAMP)) +
                      (fmaxf(__logf(a2), LOG_CLAMP) + fmaxf(__logf(a3), LOG_CLAMP));
                v1 = fmaf(p0, q0, fmaf(p1, q1, fmaf(p2, q2, fmaf(p3, q3, v1))));
                v2 += (p0 + p1) + (p2 + p3);
                v3 += (q0 + q1) + (q2 + q3);
                idx += step;
                if (idx >= N4) break;
                c += dc; r += dr;
                if (c >= W4) { c -= W4; ++r; }
            }
        }
    }

    // block reduce 256 -> 4 sums
    for (int o = 32; o > 0; o >>= 1) {
        v0 += __shfl_down(v0, o, 64);
        v1 += __shfl_down(v1, o, 64);
        v2 += __shfl_down(v2, o, 64);
        v3 += __shfl_down(v3, o, 64);
    }
    __shared__ float red[4][4];
    int lane = threadIdx.x & 63, w = threadIdx.x >> 6;
    if (lane == 0) { red[w][0] = v0; red[w][1] = v1; red[w][2] = v2; red[w][3] = v3; }
    __syncthreads();
    if (threadIdx.x < 4) {
        float sfin = red[0][threadIdx.x] + red[1][threadIdx.x] +
                     red[2][threadIdx.x] + red[3][threadIdx.x];
        acc[((size_t)obj * SPLIT + part) * 4 + threadIdx.x] = sfin;  // unconditional slot write
    }
}

__global__ __launch_bounds__(128) void finalize_kernel(
    const float* __restrict__ acc,
    const float* __restrict__ pred_boxes, const float* __restrict__ gt_boxes,
    const int* __restrict__ pred_valid, const int* __restrict__ gt_valid,
    float* __restrict__ out) {
    int i = threadIdx.x;  // 128 threads, 2 waves
    float loss = 0.0f, nk = 0.0f;
    if (i < NOBJ) {
        int keep, gidx, y1, x1, y2, x2;
        match_obj(pred_boxes, gt_boxes, pred_valid, gt_valid, i, keep, gidx, y1, x1, y2, x2);
        if (keep) {
            nk = 1.0f;
            float s0 = 0.0f, s1 = 0.0f, s2 = 0.0f, s3 = 0.0f;
            const float* a = acc + (size_t)i * SPLIT * 4;
            #pragma unroll
            for (int p = 0; p < SPLIT; ++p) {
                s0 += a[p * 4 + 0];
                s1 += a[p * 4 + 1];
                s2 += a[p * 4 + 2];
                s3 += a[p * 4 + 3];
            }
            float cnt = (y2 >= y1 && x2 >= x1) ? (float)((y2 - y1 + 1) * (x2 - x1 + 1)) : 0.0f;
            float bce = s0 / fmaxf(cnt, 1.0f);
            float dice = 1.0f - (2.0f * s1 + 1.0f) / (s2 + s3 + 1.0f);
            loss = bce + dice;
        }
    }
    float v0 = loss, v1 = nk;
    for (int o = 32; o > 0; o >>= 1) {
        v0 += __shfl_down(v0, o, 64);
        v1 += __shfl_down(v1, o, 64);
    }
    __shared__ float red[2][2];
    if ((threadIdx.x & 63) == 0) { red[threadIdx.x >> 6][0] = v0; red[threadIdx.x >> 6][1] = v1; }
    __syncthreads();
    if (threadIdx.x == 0) {
        float total = red[0][0] + red[1][0];
        float nobj = red[0][1] + red[1][1];
        out[0] = total / fmaxf(nobj, 1.0f);
    }
}

extern "C" void kernel_launch(void* const* d_in, const int* in_sizes, int n_in,
                              void* d_out, int out_size, void* d_ws, size_t ws_size,
                              hipStream_t stream) {
    const float* pred_masks = (const float*)d_in[0];
    const float* pred_boxes = (const float*)d_in[1];
    const float* gt_boxes   = (const float*)d_in[2];
    const float* gt_masks   = (const float*)d_in[3];
    const int*   pred_valid = (const int*)d_in[4];
    const int*   gt_valid   = (const int*)d_in[5];
    float* out = (float*)d_out;
    float* acc = (float*)d_ws;  // [NOBJ][SPLIT][4]

    region_kernel<<<dim3(NOBJ, SPLIT), 256, 0, stream>>>(
        pred_masks, gt_masks, pred_boxes, gt_boxes, pred_valid, gt_valid, acc);
    finalize_kernel<<<1, 128, 0, stream>>>(
        acc, pred_boxes, gt_boxes, pred_valid, gt_valid, out);
}